// Round 1
// baseline (409.918 us; speedup 1.0000x reference)
//
#include <hip/hip_runtime.h>
#include <hip/hip_bf16.h>
#include <stdint.h>

#define N_NODES   50000
#define N_EDGES   800000
#define F_IN      64
#define HID       128
#define N_CLASSES 10
#define NUM_GRAPHS 512

// ---------------------------------------------------------------- utilities
__global__ __launch_bounds__(256) void zero_int_kernel(int* p, int n) {
    int i = blockIdx.x * 256 + threadIdx.x;
    if (i < n) p[i] = 0;
}

// count in-degree (dst occurrences) of real edges
__global__ __launch_bounds__(256) void hist_kernel(const int* __restrict__ dst,
                                                   int* __restrict__ cnt, int E) {
    int e = blockIdx.x * 256 + threadIdx.x;
    if (e < E) atomicAdd(&cnt[dst[e]], 1);
}

// dinv = (deg+1)^-0.5   (+1 = self loop)
__global__ __launch_bounds__(256) void dinv_kernel(const int* __restrict__ cnt,
                                                   float* __restrict__ dinv, int N) {
    int i = blockIdx.x * 256 + threadIdx.x;
    if (i < N) dinv[i] = rsqrtf((float)(cnt[i] + 1));
}

// ------------------------------------------------------------ prefix scan (3 kernels)
__global__ __launch_bounds__(256) void scan1_kernel(const int* __restrict__ cnt,
                                                    int* __restrict__ rowptr,
                                                    int* __restrict__ bsum, int N) {
    __shared__ int s[256];
    int t = threadIdx.x;
    int i = blockIdx.x * 256 + t;
    int v = (i < N) ? cnt[i] : 0;
    s[t] = v;
    __syncthreads();
    #pragma unroll
    for (int d = 1; d < 256; d <<= 1) {
        int a = (t >= d) ? s[t - d] : 0;
        __syncthreads();
        s[t] += a;
        __syncthreads();
    }
    if (i < N) rowptr[i + 1] = s[t];   // inclusive, pre-offset
    if (t == 255) bsum[blockIdx.x] = s[255];
}

__global__ __launch_bounds__(256) void scan2_kernel(int* __restrict__ bsum, int NB) {
    __shared__ int s[256];
    int t = threadIdx.x;
    int v = (t < NB) ? bsum[t] : 0;
    s[t] = v;
    __syncthreads();
    #pragma unroll
    for (int d = 1; d < 256; d <<= 1) {
        int a = (t >= d) ? s[t - d] : 0;
        __syncthreads();
        s[t] += a;
        __syncthreads();
    }
    if (t < NB) bsum[t] = s[t] - v;    // exclusive block offset
}

__global__ __launch_bounds__(256) void scan3_kernel(const int* __restrict__ cnt,
                                                    int* __restrict__ rowptr,
                                                    const int* __restrict__ bsum,
                                                    int* __restrict__ cursor, int N) {
    int i = blockIdx.x * 256 + threadIdx.x;
    if (i < N) {
        int inc = rowptr[i + 1] + bsum[blockIdx.x];
        rowptr[i + 1] = inc;
        cursor[i] = inc - cnt[i];      // exclusive prefix = row start
    }
    if (i == 0) rowptr[0] = 0;
}

// place edges into CSR slots, precompute norm = dinv[src]*dinv[dst]
__global__ __launch_bounds__(256) void scatter_kernel(const int* __restrict__ src,
                                                      const int* __restrict__ dst,
                                                      const float* __restrict__ dinv,
                                                      int* __restrict__ cursor,
                                                      int* __restrict__ col,
                                                      float* __restrict__ enorm, int E) {
    int e = blockIdx.x * 256 + threadIdx.x;
    if (e < E) {
        int s = src[e], d = dst[e];
        int slot = atomicAdd(&cursor[d], 1);
        col[slot] = s;
        enorm[slot] = dinv[s] * dinv[d];
    }
}

// ---------------------------------------------------------------- SpMM
// out[n] = selfnorm*Hin[n] + sum_e norm_e * Hin[col_e]  (+ bias, relu optional)
// one wave per dst node, VEC floats per lane (VEC*64 = row width)
template <int VEC>
__global__ __launch_bounds__(256) void spmm_kernel(const int* __restrict__ rowptr,
                                                   const int* __restrict__ col,
                                                   const float* __restrict__ enorm,
                                                   const float* __restrict__ dinv,
                                                   const float* __restrict__ Hin,
                                                   const float* __restrict__ bias,
                                                   float* __restrict__ Hout,
                                                   int N, int applyRelu) {
    constexpr int Wd = VEC * 64;
    int wave = threadIdx.x >> 6;
    int lane = threadIdx.x & 63;
    int node = blockIdx.x * 4 + wave;
    if (node >= N) return;

    float acc[VEC];
    float di = dinv[node];
    float sn = di * di;
    const float* hrow = Hin + (size_t)node * Wd + lane * VEC;
    #pragma unroll
    for (int v = 0; v < VEC; v++) acc[v] = sn * hrow[v];

    int e  = rowptr[node];
    int e1 = rowptr[node + 1];
    for (; e + 2 <= e1; e += 2) {
        int   s0 = col[e],     s1 = col[e + 1];
        float n0 = enorm[e],   n1 = enorm[e + 1];
        const float* p0 = Hin + (size_t)s0 * Wd + lane * VEC;
        const float* p1 = Hin + (size_t)s1 * Wd + lane * VEC;
        float t0[VEC], t1[VEC];
        #pragma unroll
        for (int v = 0; v < VEC; v++) t0[v] = p0[v];
        #pragma unroll
        for (int v = 0; v < VEC; v++) t1[v] = p1[v];
        #pragma unroll
        for (int v = 0; v < VEC; v++) acc[v] = fmaf(n0, t0[v], fmaf(n1, t1[v], acc[v]));
    }
    if (e < e1) {
        int   s0 = col[e];
        float n0 = enorm[e];
        const float* p0 = Hin + (size_t)s0 * Wd + lane * VEC;
        #pragma unroll
        for (int v = 0; v < VEC; v++) acc[v] = fmaf(n0, p0[v], acc[v]);
    }

    float* orow = Hout + (size_t)node * Wd + lane * VEC;
    #pragma unroll
    for (int v = 0; v < VEC; v++) {
        float r = acc[v];
        if (bias) r += bias[lane * VEC + v];
        if (applyRelu) r = fmaxf(r, 0.0f);
        orow[v] = r;
    }
}

// ---------------------------------------------------------------- dense GEMM
// out[n][j] = (relu)( sum_k A[n][k] * W[k][j] + bias[j] ),  j in [0,128)
// block = 256 threads, tile = 32 nodes x 128 cols, K chunked by 64
template <int K>
__global__ __launch_bounds__(256) void gemm_kernel(const float* __restrict__ A,
                                                   const float* __restrict__ Wm,
                                                   const float* __restrict__ bias,
                                                   float* __restrict__ out,
                                                   int N, int applyRelu) {
    constexpr int KC = 64;
    __shared__ float Wl[KC][128];
    __shared__ float Al[32][KC + 4];

    int t = threadIdx.x;
    int tileBase = blockIdx.x * 32;
    int cj = (t & 31) * 4;        // column 0..124
    int nb = (t >> 5) * 4;        // node offset in tile 0,4,..,28

    float4 acc[4];
    #pragma unroll
    for (int nn = 0; nn < 4; nn++) acc[nn] = make_float4(0.f, 0.f, 0.f, 0.f);

    for (int kc = 0; kc < K; kc += KC) {
        // stage W chunk (KC x 128)
        const float4* Wg = (const float4*)(Wm + (size_t)kc * 128);
        #pragma unroll
        for (int i = 0; i < (KC * 128 / 4) / 256; i++) {
            int idx = i * 256 + t;
            ((float4*)Wl)[idx] = Wg[idx];
        }
        // stage A tile (32 x KC)
        #pragma unroll
        for (int i = 0; i < (32 * KC / 4) / 256; i++) {
            int fi = i * 256 + t;
            int r  = fi / (KC / 4);
            int c4 = fi % (KC / 4);
            int node = tileBase + r;
            float4 v = make_float4(0.f, 0.f, 0.f, 0.f);
            if (node < N) v = ((const float4*)(A + (size_t)node * K + kc))[c4];
            *(float4*)&Al[r][c4 * 4] = v;
        }
        __syncthreads();

        #pragma unroll
        for (int k = 0; k < KC; k += 4) {
            const float4 w0 = *(const float4*)&Wl[k + 0][cj];
            const float4 w1 = *(const float4*)&Wl[k + 1][cj];
            const float4 w2 = *(const float4*)&Wl[k + 2][cj];
            const float4 w3 = *(const float4*)&Wl[k + 3][cj];
            #pragma unroll
            for (int nn = 0; nn < 4; nn++) {
                const float4 h = *(const float4*)&Al[nb + nn][k];
                acc[nn].x = fmaf(h.x, w0.x, fmaf(h.y, w1.x, fmaf(h.z, w2.x, fmaf(h.w, w3.x, acc[nn].x))));
                acc[nn].y = fmaf(h.x, w0.y, fmaf(h.y, w1.y, fmaf(h.z, w2.y, fmaf(h.w, w3.y, acc[nn].y))));
                acc[nn].z = fmaf(h.x, w0.z, fmaf(h.y, w1.z, fmaf(h.z, w2.z, fmaf(h.w, w3.z, acc[nn].z))));
                acc[nn].w = fmaf(h.x, w0.w, fmaf(h.y, w1.w, fmaf(h.z, w2.w, fmaf(h.w, w3.w, acc[nn].w))));
            }
        }
        __syncthreads();
    }

    float4 bv = make_float4(0.f, 0.f, 0.f, 0.f);
    if (bias) bv = *(const float4*)(bias + cj);
    #pragma unroll
    for (int nn = 0; nn < 4; nn++) {
        int node = tileBase + nb + nn;
        if (node < N) {
            float4 r;
            r.x = acc[nn].x + bv.x;
            r.y = acc[nn].y + bv.y;
            r.z = acc[nn].z + bv.z;
            r.w = acc[nn].w + bv.w;
            if (applyRelu) {
                r.x = fmaxf(r.x, 0.f); r.y = fmaxf(r.y, 0.f);
                r.z = fmaxf(r.z, 0.f); r.w = fmaxf(r.w, 0.f);
            }
            ((float4*)out)[(size_t)node * 32 + (cj >> 2)] = r;
        }
    }
}

// ---------------------------------------------------------------- pool + MLP
__device__ __forceinline__ int lowerb(const int* a, int n, int v) {
    int lo = 0, hi = n;
    while (lo < hi) {
        int m = (lo + hi) >> 1;
        if (a[m] < v) lo = m + 1; else hi = m;
    }
    return lo;
}

// one block (128 threads) per graph: sum node rows, then 128->128->128->10 MLP
__global__ __launch_bounds__(128) void pool_mlp_kernel(const float* __restrict__ H,
                                                       const int* __restrict__ batch,
                                                       const float* __restrict__ mW0, const float* __restrict__ mb0,
                                                       const float* __restrict__ mW1, const float* __restrict__ mb1,
                                                       const float* __restrict__ mW2, const float* __restrict__ mb2,
                                                       float* __restrict__ out, int N) {
    int b = blockIdx.x;
    int j = threadIdx.x;
    int lo = lowerb(batch, N, b);
    int hi = lowerb(batch, N, b + 1);

    float s = 0.f;
    for (int n = lo; n < hi; n++) s += H[(size_t)n * HID + j];

    __shared__ float l0[HID];
    __shared__ float l1[HID];
    l0[j] = s;
    __syncthreads();

    float a = mb0[j];
    #pragma unroll 8
    for (int k = 0; k < HID; k++) a = fmaf(l0[k], mW0[k * HID + j], a);
    a = fmaxf(a, 0.f);
    l1[j] = a;
    __syncthreads();

    float c = mb1[j];
    #pragma unroll 8
    for (int k = 0; k < HID; k++) c = fmaf(l1[k], mW1[k * HID + j], c);
    c = fmaxf(c, 0.f);
    __syncthreads();           // l0 reads of layer-1 are long done; safe to overwrite
    l0[j] = c;
    __syncthreads();

    if (j < N_CLASSES) {
        float d = mb2[j];
        #pragma unroll 8
        for (int k = 0; k < HID; k++) d = fmaf(l0[k], mW2[k * N_CLASSES + j], d);
        out[b * N_CLASSES + j] = d;
    }
}

// ---------------------------------------------------------------- launch
extern "C" void kernel_launch(void* const* d_in, const int* in_sizes, int n_in,
                              void* d_out, int out_size, void* d_ws, size_t ws_size,
                              hipStream_t stream) {
    const float* x     = (const float*)d_in[0];
    const int*   ei    = (const int*)d_in[1];
    const int*   batch = (const int*)d_in[2];
    const float* W0  = (const float*)d_in[3];
    const float* b0  = (const float*)d_in[4];
    const float* W1  = (const float*)d_in[5];
    const float* b1  = (const float*)d_in[6];
    const float* W2  = (const float*)d_in[7];
    const float* b2  = (const float*)d_in[8];
    const float* mW0 = (const float*)d_in[9];
    const float* mb0 = (const float*)d_in[10];
    const float* mW1 = (const float*)d_in[11];
    const float* mb1 = (const float*)d_in[12];
    const float* mW2 = (const float*)d_in[13];
    const float* mb2 = (const float*)d_in[14];
    float* out = (float*)d_out;

    const int N = N_NODES, E = N_EDGES;
    const int* src = ei;
    const int* dst = ei + E;

    // workspace carve (256B aligned)
    char* w = (char*)d_ws;
    auto alloc = [&](size_t bytes) -> void* {
        void* p = (void*)w;
        w += (bytes + 255) & ~(size_t)255;
        return p;
    };
    int*   cnt    = (int*)alloc((size_t)N * 4);
    int*   rowptr = (int*)alloc((size_t)(N + 1) * 4);
    int*   cursor = (int*)alloc((size_t)N * 4);
    int*   col    = (int*)alloc((size_t)E * 4);
    float* enorm  = (float*)alloc((size_t)E * 4);
    float* dinv   = (float*)alloc((size_t)N * 4);
    int*   bsum   = (int*)alloc(256 * 4);
    float* bufA   = (float*)alloc((size_t)N * HID * 4);
    float* bufB   = (float*)alloc((size_t)N * HID * 4);

    const int NB  = (N + 255) / 256;   // 196
    const int EB  = (E + 255) / 256;   // 3125
    const int SPB = (N + 3) / 4;       // 12500
    const int GB  = (N + 31) / 32;     // 1563

    // ---- CSR build
    zero_int_kernel<<<NB, 256, 0, stream>>>(cnt, N);
    hist_kernel<<<EB, 256, 0, stream>>>(dst, cnt, E);
    dinv_kernel<<<NB, 256, 0, stream>>>(cnt, dinv, N);
    scan1_kernel<<<NB, 256, 0, stream>>>(cnt, rowptr, bsum, N);
    scan2_kernel<<<1, 256, 0, stream>>>(bsum, NB);
    scan3_kernel<<<NB, 256, 0, stream>>>(cnt, rowptr, bsum, cursor, N);
    scatter_kernel<<<EB, 256, 0, stream>>>(src, dst, dinv, cursor, col, enorm, E);

    // ---- layer 0: aggregate raw x (A@x), then GEMM with bias+relu
    spmm_kernel<1><<<SPB, 256, 0, stream>>>(rowptr, col, enorm, dinv, x, nullptr, bufA, N, 0);
    gemm_kernel<64><<<GB, 256, 0, stream>>>(bufA, W0, b0, bufB, N, 1);

    // ---- layer 1: t = h0@W1, h1 = relu(A@t + b1)
    gemm_kernel<128><<<GB, 256, 0, stream>>>(bufB, W1, nullptr, bufA, N, 0);
    spmm_kernel<2><<<SPB, 256, 0, stream>>>(rowptr, col, enorm, dinv, bufA, b1, bufB, N, 1);

    // ---- layer 2: t = h1@W2, h2 = relu(A@t + b2)
    gemm_kernel<128><<<GB, 256, 0, stream>>>(bufB, W2, nullptr, bufA, N, 0);
    spmm_kernel<2><<<SPB, 256, 0, stream>>>(rowptr, col, enorm, dinv, bufA, b2, bufB, N, 1);

    // ---- pool + MLP
    pool_mlp_kernel<<<NUM_GRAPHS, 128, 0, stream>>>(bufB, batch, mW0, mb0, mW1, mb1, mW2, mb2, out, N);
}

// Round 2
// 354.699 us; speedup vs baseline: 1.1557x; 1.1557x over previous
//
#include <hip/hip_runtime.h>
#include <hip/hip_bf16.h>
#include <stdint.h>

#define N_NODES   50000
#define N_EDGES   800000
#define F_IN      64
#define HID       128
#define N_CLASSES 10
#define NUM_GRAPHS 512

// ---------------------------------------------------------------- utilities
__global__ __launch_bounds__(256) void zero_int_kernel(int* p, int n) {
    int i = blockIdx.x * 256 + threadIdx.x;
    if (i < n) p[i] = 0;
}

// count in-degree (dst occurrences) of real edges
__global__ __launch_bounds__(256) void hist_kernel(const int* __restrict__ dst,
                                                   int* __restrict__ cnt, int E) {
    int e = blockIdx.x * 256 + threadIdx.x;
    if (e < E) atomicAdd(&cnt[dst[e]], 1);
}

// ------------------------------------------------------------ prefix scan (3 kernels)
__global__ __launch_bounds__(256) void scan1_kernel(const int* __restrict__ cnt,
                                                    int* __restrict__ rowptr,
                                                    int* __restrict__ bsum, int N) {
    __shared__ int s[256];
    int t = threadIdx.x;
    int i = blockIdx.x * 256 + t;
    int v = (i < N) ? cnt[i] : 0;
    s[t] = v;
    __syncthreads();
    #pragma unroll
    for (int d = 1; d < 256; d <<= 1) {
        int a = (t >= d) ? s[t - d] : 0;
        __syncthreads();
        s[t] += a;
        __syncthreads();
    }
    if (i < N) rowptr[i + 1] = s[t];   // inclusive, pre-offset
    if (t == 255) bsum[blockIdx.x] = s[255];
}

__global__ __launch_bounds__(256) void scan2_kernel(int* __restrict__ bsum, int NB) {
    __shared__ int s[256];
    int t = threadIdx.x;
    int v = (t < NB) ? bsum[t] : 0;
    s[t] = v;
    __syncthreads();
    #pragma unroll
    for (int d = 1; d < 256; d <<= 1) {
        int a = (t >= d) ? s[t - d] : 0;
        __syncthreads();
        s[t] += a;
        __syncthreads();
    }
    if (t < NB) bsum[t] = s[t] - v;    // exclusive block offset
}

// rowptr finalize + cursor + dinv (folded)
__global__ __launch_bounds__(256) void scan3_kernel(const int* __restrict__ cnt,
                                                    int* __restrict__ rowptr,
                                                    const int* __restrict__ bsum,
                                                    int* __restrict__ cursor,
                                                    float* __restrict__ dinv, int N) {
    int i = blockIdx.x * 256 + threadIdx.x;
    if (i < N) {
        int c = cnt[i];
        int inc = rowptr[i + 1] + bsum[blockIdx.x];
        rowptr[i + 1] = inc;
        cursor[i] = inc - c;           // exclusive prefix = row start
        dinv[i] = rsqrtf((float)(c + 1));
    }
    if (i == 0) rowptr[0] = 0;
}

// place edges into CSR slots; meta = (src, norm) packed 8B
__global__ __launch_bounds__(256) void scatter_kernel(const int* __restrict__ src,
                                                      const int* __restrict__ dst,
                                                      const float* __restrict__ dinv,
                                                      int* __restrict__ cursor,
                                                      int2* __restrict__ meta, int E) {
    int e = blockIdx.x * 256 + threadIdx.x;
    if (e < E) {
        int s = src[e], d = dst[e];
        int slot = atomicAdd(&cursor[d], 1);
        meta[slot] = make_int2(s, __float_as_int(dinv[s] * dinv[d]));
    }
}

// ---------------------------------------------------------------- SpMM (128-wide)
// one wave per node; lane = 32*half + sub; each lane holds float4 chunk `sub`
// of the row for edge-parity `half` -> 2 edges per row-load instruction,
// 4 edges (2 loads/lane) in flight per loop iteration.
__global__ __launch_bounds__(256) void spmm128_kernel(const int* __restrict__ rowptr,
                                                      const int2* __restrict__ meta,
                                                      const float* __restrict__ dinv,
                                                      const float* __restrict__ Hin,
                                                      const float* __restrict__ bias,
                                                      float* __restrict__ Hout,
                                                      int N, int applyRelu) {
    int wave = threadIdx.x >> 6;
    int lane = threadIdx.x & 63;
    int node = blockIdx.x * 4 + wave;
    if (node >= N) return;
    int half = lane >> 5;
    int sub  = lane & 31;

    const float4* Hv = (const float4*)Hin;     // row stride = 32 float4
    float di = dinv[node];
    float sn = di * di;

    float4 self = Hv[(size_t)node * 32 + sub];
    float w0 = half ? 0.0f : sn;
    float4 acc = make_float4(w0 * self.x, w0 * self.y, w0 * self.z, w0 * self.w);

    int e0 = rowptr[node];
    int e1 = rowptr[node + 1];
    for (int e = e0; e < e1; e += 4) {
        int i0 = e + half;
        int i1 = e + 2 + half;
        int2 m0 = (i0 < e1) ? meta[i0] : make_int2(0, 0);   // norm=0 -> no-op
        int2 m1 = (i1 < e1) ? meta[i1] : make_int2(0, 0);
        float n0 = __int_as_float(m0.y);
        float n1 = __int_as_float(m1.y);
        float4 r0 = Hv[(size_t)m0.x * 32 + sub];
        float4 r1 = Hv[(size_t)m1.x * 32 + sub];
        acc.x = fmaf(n0, r0.x, acc.x);
        acc.y = fmaf(n0, r0.y, acc.y);
        acc.z = fmaf(n0, r0.z, acc.z);
        acc.w = fmaf(n0, r0.w, acc.w);
        acc.x = fmaf(n1, r1.x, acc.x);
        acc.y = fmaf(n1, r1.y, acc.y);
        acc.z = fmaf(n1, r1.z, acc.z);
        acc.w = fmaf(n1, r1.w, acc.w);
    }

    // combine half 0 + half 1
    acc.x += __shfl_xor(acc.x, 32);
    acc.y += __shfl_xor(acc.y, 32);
    acc.z += __shfl_xor(acc.z, 32);
    acc.w += __shfl_xor(acc.w, 32);

    if (half == 0) {
        if (bias) {
            float4 bv = ((const float4*)bias)[sub];
            acc.x += bv.x; acc.y += bv.y; acc.z += bv.z; acc.w += bv.w;
        }
        if (applyRelu) {
            acc.x = fmaxf(acc.x, 0.f); acc.y = fmaxf(acc.y, 0.f);
            acc.z = fmaxf(acc.z, 0.f); acc.w = fmaxf(acc.w, 0.f);
        }
        ((float4*)Hout)[(size_t)node * 32 + sub] = acc;
    }
}

// ---------------------------------------------------------------- SpMM (64-wide)
// lane = 16*q + sub; 4 edges per row-load instruction, 8 edges per iteration.
__global__ __launch_bounds__(256) void spmm64_kernel(const int* __restrict__ rowptr,
                                                     const int2* __restrict__ meta,
                                                     const float* __restrict__ dinv,
                                                     const float* __restrict__ Hin,
                                                     float* __restrict__ Hout, int N) {
    int wave = threadIdx.x >> 6;
    int lane = threadIdx.x & 63;
    int node = blockIdx.x * 4 + wave;
    if (node >= N) return;
    int q   = lane >> 4;
    int sub = lane & 15;

    const float4* Hv = (const float4*)Hin;     // row stride = 16 float4
    float di = dinv[node];
    float sn = di * di;

    float4 self = Hv[(size_t)node * 16 + sub];
    float w0 = (q == 0) ? sn : 0.0f;
    float4 acc = make_float4(w0 * self.x, w0 * self.y, w0 * self.z, w0 * self.w);

    int e0 = rowptr[node];
    int e1 = rowptr[node + 1];
    for (int e = e0; e < e1; e += 8) {
        int i0 = e + q;
        int i1 = e + 4 + q;
        int2 m0 = (i0 < e1) ? meta[i0] : make_int2(0, 0);
        int2 m1 = (i1 < e1) ? meta[i1] : make_int2(0, 0);
        float n0 = __int_as_float(m0.y);
        float n1 = __int_as_float(m1.y);
        float4 r0 = Hv[(size_t)m0.x * 16 + sub];
        float4 r1 = Hv[(size_t)m1.x * 16 + sub];
        acc.x = fmaf(n0, r0.x, acc.x);
        acc.y = fmaf(n0, r0.y, acc.y);
        acc.z = fmaf(n0, r0.z, acc.z);
        acc.w = fmaf(n0, r0.w, acc.w);
        acc.x = fmaf(n1, r1.x, acc.x);
        acc.y = fmaf(n1, r1.y, acc.y);
        acc.z = fmaf(n1, r1.z, acc.z);
        acc.w = fmaf(n1, r1.w, acc.w);
    }

    acc.x += __shfl_xor(acc.x, 16);
    acc.y += __shfl_xor(acc.y, 16);
    acc.z += __shfl_xor(acc.z, 16);
    acc.w += __shfl_xor(acc.w, 16);
    acc.x += __shfl_xor(acc.x, 32);
    acc.y += __shfl_xor(acc.y, 32);
    acc.z += __shfl_xor(acc.z, 32);
    acc.w += __shfl_xor(acc.w, 32);

    if (q == 0) {
        ((float4*)Hout)[(size_t)node * 16 + sub] = acc;
    }
}

// ---------------------------------------------------------------- dense GEMM
// out[n][j] = (relu)( sum_k A[n][k] * W[k][j] + bias[j] ),  j in [0,128)
template <int K>
__global__ __launch_bounds__(256) void gemm_kernel(const float* __restrict__ A,
                                                   const float* __restrict__ Wm,
                                                   const float* __restrict__ bias,
                                                   float* __restrict__ out,
                                                   int N, int applyRelu) {
    constexpr int KC = 64;
    __shared__ float Wl[KC][128];
    __shared__ float Al[32][KC + 4];

    int t = threadIdx.x;
    int tileBase = blockIdx.x * 32;
    int cj = (t & 31) * 4;
    int nb = (t >> 5) * 4;

    float4 acc[4];
    #pragma unroll
    for (int nn = 0; nn < 4; nn++) acc[nn] = make_float4(0.f, 0.f, 0.f, 0.f);

    for (int kc = 0; kc < K; kc += KC) {
        const float4* Wg = (const float4*)(Wm + (size_t)kc * 128);
        #pragma unroll
        for (int i = 0; i < (KC * 128 / 4) / 256; i++) {
            int idx = i * 256 + t;
            ((float4*)Wl)[idx] = Wg[idx];
        }
        #pragma unroll
        for (int i = 0; i < (32 * KC / 4) / 256; i++) {
            int fi = i * 256 + t;
            int r  = fi / (KC / 4);
            int c4 = fi % (KC / 4);
            int node = tileBase + r;
            float4 v = make_float4(0.f, 0.f, 0.f, 0.f);
            if (node < N) v = ((const float4*)(A + (size_t)node * K + kc))[c4];
            *(float4*)&Al[r][c4 * 4] = v;
        }
        __syncthreads();

        #pragma unroll
        for (int k = 0; k < KC; k += 4) {
            const float4 w0 = *(const float4*)&Wl[k + 0][cj];
            const float4 w1 = *(const float4*)&Wl[k + 1][cj];
            const float4 w2 = *(const float4*)&Wl[k + 2][cj];
            const float4 w3 = *(const float4*)&Wl[k + 3][cj];
            #pragma unroll
            for (int nn = 0; nn < 4; nn++) {
                const float4 h = *(const float4*)&Al[nb + nn][k];
                acc[nn].x = fmaf(h.x, w0.x, fmaf(h.y, w1.x, fmaf(h.z, w2.x, fmaf(h.w, w3.x, acc[nn].x))));
                acc[nn].y = fmaf(h.x, w0.y, fmaf(h.y, w1.y, fmaf(h.z, w2.y, fmaf(h.w, w3.y, acc[nn].y))));
                acc[nn].z = fmaf(h.x, w0.z, fmaf(h.y, w1.z, fmaf(h.z, w2.z, fmaf(h.w, w3.z, acc[nn].z))));
                acc[nn].w = fmaf(h.x, w0.w, fmaf(h.y, w1.w, fmaf(h.z, w2.w, fmaf(h.w, w3.w, acc[nn].w))));
            }
        }
        __syncthreads();
    }

    float4 bv = make_float4(0.f, 0.f, 0.f, 0.f);
    if (bias) bv = *(const float4*)(bias + cj);
    #pragma unroll
    for (int nn = 0; nn < 4; nn++) {
        int node = tileBase + nb + nn;
        if (node < N) {
            float4 r;
            r.x = acc[nn].x + bv.x;
            r.y = acc[nn].y + bv.y;
            r.z = acc[nn].z + bv.z;
            r.w = acc[nn].w + bv.w;
            if (applyRelu) {
                r.x = fmaxf(r.x, 0.f); r.y = fmaxf(r.y, 0.f);
                r.z = fmaxf(r.z, 0.f); r.w = fmaxf(r.w, 0.f);
            }
            ((float4*)out)[(size_t)node * 32 + (cj >> 2)] = r;
        }
    }
}

// ---------------------------------------------------------------- pool + MLP
__device__ __forceinline__ int lowerb(const int* a, int n, int v) {
    int lo = 0, hi = n;
    while (lo < hi) {
        int m = (lo + hi) >> 1;
        if (a[m] < v) lo = m + 1; else hi = m;
    }
    return lo;
}

// one block (256 threads) per graph: 2-way split pooling, then 128->128->128->10 MLP
__global__ __launch_bounds__(256) void pool_mlp_kernel(const float* __restrict__ H,
                                                       const int* __restrict__ batch,
                                                       const float* __restrict__ mW0, const float* __restrict__ mb0,
                                                       const float* __restrict__ mW1, const float* __restrict__ mb1,
                                                       const float* __restrict__ mW2, const float* __restrict__ mb2,
                                                       float* __restrict__ out, int N) {
    int b = blockIdx.x;
    int t = threadIdx.x;
    int j = t & 127;
    int g = t >> 7;
    int lo = lowerb(batch, N, b);
    int hi = lowerb(batch, N, b + 1);

    float s0 = 0.f, s1 = 0.f;
    for (int n = lo + g; n + 2 < hi; n += 4) {
        s0 += H[(size_t)n * HID + j];
        s1 += H[(size_t)(n + 2) * HID + j];
    }
    // tail for this parity
    {
        int done = lo + g;
        int cnt4 = 0;
        for (int n = lo + g; n + 2 < hi; n += 4) cnt4++;
        done = lo + g + cnt4 * 4;
        for (int n = done; n < hi; n += 2) s0 += H[(size_t)n * HID + j];
    }

    __shared__ float part[2][HID];
    __shared__ float l0[HID];
    __shared__ float l1[HID];
    part[g][j] = s0 + s1;
    __syncthreads();
    if (t < 128) l0[j] = part[0][j] + part[1][j];
    __syncthreads();

    if (t < 128) {
        float a0 = mb0[j], a1 = 0.f, a2 = 0.f, a3 = 0.f;
        #pragma unroll 4
        for (int k = 0; k < HID; k += 4) {
            a0 = fmaf(l0[k + 0], mW0[(k + 0) * HID + j], a0);
            a1 = fmaf(l0[k + 1], mW0[(k + 1) * HID + j], a1);
            a2 = fmaf(l0[k + 2], mW0[(k + 2) * HID + j], a2);
            a3 = fmaf(l0[k + 3], mW0[(k + 3) * HID + j], a3);
        }
        l1[j] = fmaxf((a0 + a1) + (a2 + a3), 0.f);
    }
    __syncthreads();

    float c = 0.f;
    if (t < 128) {
        float a0 = mb1[j], a1 = 0.f, a2 = 0.f, a3 = 0.f;
        #pragma unroll 4
        for (int k = 0; k < HID; k += 4) {
            a0 = fmaf(l1[k + 0], mW1[(k + 0) * HID + j], a0);
            a1 = fmaf(l1[k + 1], mW1[(k + 1) * HID + j], a1);
            a2 = fmaf(l1[k + 2], mW1[(k + 2) * HID + j], a2);
            a3 = fmaf(l1[k + 3], mW1[(k + 3) * HID + j], a3);
        }
        c = fmaxf((a0 + a1) + (a2 + a3), 0.f);
    }
    __syncthreads();
    if (t < 128) l0[j] = c;
    __syncthreads();

    if (t < N_CLASSES) {
        float a0 = mb2[t], a1 = 0.f, a2 = 0.f, a3 = 0.f;
        #pragma unroll 4
        for (int k = 0; k < HID; k += 4) {
            a0 = fmaf(l0[k + 0], mW2[(k + 0) * N_CLASSES + t], a0);
            a1 = fmaf(l0[k + 1], mW2[(k + 1) * N_CLASSES + t], a1);
            a2 = fmaf(l0[k + 2], mW2[(k + 2) * N_CLASSES + t], a2);
            a3 = fmaf(l0[k + 3], mW2[(k + 3) * N_CLASSES + t], a3);
        }
        out[b * N_CLASSES + t] = (a0 + a1) + (a2 + a3);
    }
}

// ---------------------------------------------------------------- launch
extern "C" void kernel_launch(void* const* d_in, const int* in_sizes, int n_in,
                              void* d_out, int out_size, void* d_ws, size_t ws_size,
                              hipStream_t stream) {
    const float* x     = (const float*)d_in[0];
    const int*   ei    = (const int*)d_in[1];
    const int*   batch = (const int*)d_in[2];
    const float* W0  = (const float*)d_in[3];
    const float* b0  = (const float*)d_in[4];
    const float* W1  = (const float*)d_in[5];
    const float* b1  = (const float*)d_in[6];
    const float* W2  = (const float*)d_in[7];
    const float* b2  = (const float*)d_in[8];
    const float* mW0 = (const float*)d_in[9];
    const float* mb0 = (const float*)d_in[10];
    const float* mW1 = (const float*)d_in[11];
    const float* mb1 = (const float*)d_in[12];
    const float* mW2 = (const float*)d_in[13];
    const float* mb2 = (const float*)d_in[14];
    float* out = (float*)d_out;

    const int N = N_NODES, E = N_EDGES;
    const int* src = ei;
    const int* dst = ei + E;

    char* w = (char*)d_ws;
    auto alloc = [&](size_t bytes) -> void* {
        void* p = (void*)w;
        w += (bytes + 255) & ~(size_t)255;
        return p;
    };
    int*   cnt    = (int*)alloc((size_t)N * 4);
    int*   rowptr = (int*)alloc((size_t)(N + 1) * 4);
    int*   cursor = (int*)alloc((size_t)N * 4);
    int2*  meta   = (int2*)alloc((size_t)E * 8);
    float* dinv   = (float*)alloc((size_t)N * 4);
    int*   bsum   = (int*)alloc(256 * 4);
    float* bufA   = (float*)alloc((size_t)N * HID * 4);
    float* bufB   = (float*)alloc((size_t)N * HID * 4);

    const int NB  = (N + 255) / 256;   // 196
    const int EB  = (E + 255) / 256;   // 3125
    const int SPB = (N + 3) / 4;       // 12500
    const int GB  = (N + 31) / 32;     // 1563

    // ---- CSR build
    zero_int_kernel<<<NB, 256, 0, stream>>>(cnt, N);
    hist_kernel<<<EB, 256, 0, stream>>>(dst, cnt, E);
    scan1_kernel<<<NB, 256, 0, stream>>>(cnt, rowptr, bsum, N);
    scan2_kernel<<<1, 256, 0, stream>>>(bsum, NB);
    scan3_kernel<<<NB, 256, 0, stream>>>(cnt, rowptr, bsum, cursor, dinv, N);
    scatter_kernel<<<EB, 256, 0, stream>>>(src, dst, dinv, cursor, meta, E);

    // ---- layer 0: aggregate raw x (A@x), then GEMM with bias+relu
    spmm64_kernel<<<SPB, 256, 0, stream>>>(rowptr, meta, dinv, x, bufA, N);
    gemm_kernel<64><<<GB, 256, 0, stream>>>(bufA, W0, b0, bufB, N, 1);

    // ---- layer 1: t = h0@W1, h1 = relu(A@t + b1)
    gemm_kernel<128><<<GB, 256, 0, stream>>>(bufB, W1, nullptr, bufA, N, 0);
    spmm128_kernel<<<SPB, 256, 0, stream>>>(rowptr, meta, dinv, bufA, b1, bufB, N, 1);

    // ---- layer 2: t = h1@W2, h2 = relu(A@t + b2)
    gemm_kernel<128><<<GB, 256, 0, stream>>>(bufB, W2, nullptr, bufA, N, 0);
    spmm128_kernel<<<SPB, 256, 0, stream>>>(rowptr, meta, dinv, bufA, b2, bufB, N, 1);

    // ---- pool + MLP
    pool_mlp_kernel<<<NUM_GRAPHS, 256, 0, stream>>>(bufB, batch, mW0, mb0, mW1, mb1, mW2, mb2, out, N);
}

// Round 3
// 320.460 us; speedup vs baseline: 1.2792x; 1.1068x over previous
//
#include <hip/hip_runtime.h>
#include <hip/hip_bf16.h>
#include <stdint.h>

#define N_NODES   50000
#define N_EDGES   800000
#define F_IN      64
#define HID       128
#define N_CLASSES 10
#define NUM_GRAPHS 512

typedef unsigned int uint32;

// ---------------- bf16 helpers (storage bf16, math fp32) ----------------
__device__ __forceinline__ float bl(uint32 w) { return __uint_as_float(w << 16); }
__device__ __forceinline__ float bh(uint32 w) { return __uint_as_float(w & 0xffff0000u); }
__device__ __forceinline__ uint32 packbf(float a, float b) {   // RNE, (a=low, b=high)
    uint32 ua = __float_as_uint(a), ub = __float_as_uint(b);
    ua = (ua + 0x7fffu + ((ua >> 16) & 1u)) >> 16;
    ub = (ub + 0x7fffu + ((ub >> 16) & 1u)) >> 16;
    return ua | (ub << 16);
}

// ---------------------------------------------------------------- utilities
__global__ __launch_bounds__(256) void zero_int_kernel(int* p, int n) {
    int i = blockIdx.x * 256 + threadIdx.x;
    if (i < n) p[i] = 0;
}

__global__ __launch_bounds__(256) void hist_kernel(const int* __restrict__ dst,
                                                   int* __restrict__ cnt, int E) {
    int e = blockIdx.x * 256 + threadIdx.x;
    if (e < E) atomicAdd(&cnt[dst[e]], 1);
}

// f32 -> bf16 conversion (4 elems/thread)
__global__ __launch_bounds__(256) void f2b_kernel(const float4* __restrict__ in,
                                                  uint2* __restrict__ out, int n) {
    int i = blockIdx.x * 256 + threadIdx.x;
    if (i < n) {
        float4 v = in[i];
        out[i] = make_uint2(packbf(v.x, v.y), packbf(v.z, v.w));
    }
}

// ------------------------------------------------------------ prefix scan
__global__ __launch_bounds__(256) void scan1_kernel(const int* __restrict__ cnt,
                                                    int* __restrict__ rowptr,
                                                    int* __restrict__ bsum, int N) {
    __shared__ int s[256];
    int t = threadIdx.x;
    int i = blockIdx.x * 256 + t;
    int v = (i < N) ? cnt[i] : 0;
    s[t] = v;
    __syncthreads();
    #pragma unroll
    for (int d = 1; d < 256; d <<= 1) {
        int a = (t >= d) ? s[t - d] : 0;
        __syncthreads();
        s[t] += a;
        __syncthreads();
    }
    if (i < N) rowptr[i + 1] = s[t];
    if (t == 255) bsum[blockIdx.x] = s[255];
}

__global__ __launch_bounds__(256) void scan2_kernel(int* __restrict__ bsum, int NB) {
    __shared__ int s[256];
    int t = threadIdx.x;
    int v = (t < NB) ? bsum[t] : 0;
    s[t] = v;
    __syncthreads();
    #pragma unroll
    for (int d = 1; d < 256; d <<= 1) {
        int a = (t >= d) ? s[t - d] : 0;
        __syncthreads();
        s[t] += a;
        __syncthreads();
    }
    if (t < NB) bsum[t] = s[t] - v;
}

__global__ __launch_bounds__(256) void scan3_kernel(const int* __restrict__ cnt,
                                                    int* __restrict__ rowptr,
                                                    const int* __restrict__ bsum,
                                                    int* __restrict__ cursor,
                                                    float* __restrict__ dinv, int N) {
    int i = blockIdx.x * 256 + threadIdx.x;
    if (i < N) {
        int c = cnt[i];
        int inc = rowptr[i + 1] + bsum[blockIdx.x];
        rowptr[i + 1] = inc;
        cursor[i] = inc - c;
        dinv[i] = rsqrtf((float)(c + 1));
    }
    if (i == 0) rowptr[0] = 0;
}

__global__ __launch_bounds__(256) void scatter_kernel(const int* __restrict__ src,
                                                      const int* __restrict__ dst,
                                                      const float* __restrict__ dinv,
                                                      int* __restrict__ cursor,
                                                      int2* __restrict__ meta, int E) {
    int e = blockIdx.x * 256 + threadIdx.x;
    if (e < E) {
        int s = src[e], d = dst[e];
        int slot = atomicAdd(&cursor[d], 1);
        meta[slot] = make_int2(s, __float_as_int(dinv[s] * dinv[d]));
    }
}

// ---------------------------------------------------------------- SpMM 128-wide bf16
// wave/node; lane = 16*q + sub (q=edge slot 0..3, sub=16B chunk 0..15).
// 4 edges per row-load instruction, 8 edges (2 loads deep) per iteration.
__global__ __launch_bounds__(256) void spmm128_kernel(const int* __restrict__ rowptr,
                                                      const int2* __restrict__ meta,
                                                      const float* __restrict__ dinv,
                                                      const unsigned short* __restrict__ Hin,
                                                      const float* __restrict__ bias,
                                                      unsigned short* __restrict__ Hout,
                                                      int N, int applyRelu) {
    int wave = threadIdx.x >> 6;
    int lane = threadIdx.x & 63;
    int node = blockIdx.x * 4 + wave;
    if (node >= N) return;
    int q   = lane >> 4;
    int sub = lane & 15;

    const uint4* Hv = (const uint4*)Hin;     // row = 16 chunks of 8 bf16
    float di = dinv[node];
    float sn = di * di;

    float acc[8];
    if (q == 0) {
        uint4 s = Hv[(size_t)node * 16 + sub];
        acc[0] = sn * bl(s.x); acc[1] = sn * bh(s.x);
        acc[2] = sn * bl(s.y); acc[3] = sn * bh(s.y);
        acc[4] = sn * bl(s.z); acc[5] = sn * bh(s.z);
        acc[6] = sn * bl(s.w); acc[7] = sn * bh(s.w);
    } else {
        #pragma unroll
        for (int v = 0; v < 8; v++) acc[v] = 0.f;
    }

    int e0 = rowptr[node];
    int e1 = rowptr[node + 1];
    for (int e = e0; e < e1; e += 8) {
        int i0 = e + q;
        int i1 = e + 4 + q;
        int2 m0 = (i0 < e1) ? meta[i0] : make_int2(0, 0);
        int2 m1 = (i1 < e1) ? meta[i1] : make_int2(0, 0);
        float n0 = __int_as_float(m0.y);
        float n1 = __int_as_float(m1.y);
        uint4 r0 = Hv[(size_t)m0.x * 16 + sub];
        uint4 r1 = Hv[(size_t)m1.x * 16 + sub];
        acc[0] = fmaf(n0, bl(r0.x), acc[0]); acc[1] = fmaf(n0, bh(r0.x), acc[1]);
        acc[2] = fmaf(n0, bl(r0.y), acc[2]); acc[3] = fmaf(n0, bh(r0.y), acc[3]);
        acc[4] = fmaf(n0, bl(r0.z), acc[4]); acc[5] = fmaf(n0, bh(r0.z), acc[5]);
        acc[6] = fmaf(n0, bl(r0.w), acc[6]); acc[7] = fmaf(n0, bh(r0.w), acc[7]);
        acc[0] = fmaf(n1, bl(r1.x), acc[0]); acc[1] = fmaf(n1, bh(r1.x), acc[1]);
        acc[2] = fmaf(n1, bl(r1.y), acc[2]); acc[3] = fmaf(n1, bh(r1.y), acc[3]);
        acc[4] = fmaf(n1, bl(r1.z), acc[4]); acc[5] = fmaf(n1, bh(r1.z), acc[5]);
        acc[6] = fmaf(n1, bl(r1.w), acc[6]); acc[7] = fmaf(n1, bh(r1.w), acc[7]);
    }

    #pragma unroll
    for (int v = 0; v < 8; v++) {
        acc[v] += __shfl_xor(acc[v], 16);
        acc[v] += __shfl_xor(acc[v], 32);
    }

    if (q == 0) {
        if (bias) {
            const float4* bp = (const float4*)(bias + sub * 8);
            float4 b0 = bp[0], b1 = bp[1];
            acc[0] += b0.x; acc[1] += b0.y; acc[2] += b0.z; acc[3] += b0.w;
            acc[4] += b1.x; acc[5] += b1.y; acc[6] += b1.z; acc[7] += b1.w;
        }
        if (applyRelu) {
            #pragma unroll
            for (int v = 0; v < 8; v++) acc[v] = fmaxf(acc[v], 0.f);
        }
        uint4 o;
        o.x = packbf(acc[0], acc[1]);
        o.y = packbf(acc[2], acc[3]);
        o.z = packbf(acc[4], acc[5]);
        o.w = packbf(acc[6], acc[7]);
        ((uint4*)Hout)[(size_t)node * 16 + sub] = o;
    }
}

// ---------------------------------------------------------------- SpMM 64-wide bf16
// lane = 8*oct + sub (oct=edge slot 0..7, sub=16B chunk 0..7).
// 8 edges per row-load instruction, 16 edges per iteration.
__global__ __launch_bounds__(256) void spmm64_kernel(const int* __restrict__ rowptr,
                                                     const int2* __restrict__ meta,
                                                     const float* __restrict__ dinv,
                                                     const unsigned short* __restrict__ Hin,
                                                     unsigned short* __restrict__ Hout, int N) {
    int wave = threadIdx.x >> 6;
    int lane = threadIdx.x & 63;
    int node = blockIdx.x * 4 + wave;
    if (node >= N) return;
    int oct = lane >> 3;
    int sub = lane & 7;

    const uint4* Hv = (const uint4*)Hin;     // row = 8 chunks of 8 bf16
    float di = dinv[node];
    float sn = di * di;

    float acc[8];
    if (oct == 0) {
        uint4 s = Hv[(size_t)node * 8 + sub];
        acc[0] = sn * bl(s.x); acc[1] = sn * bh(s.x);
        acc[2] = sn * bl(s.y); acc[3] = sn * bh(s.y);
        acc[4] = sn * bl(s.z); acc[5] = sn * bh(s.z);
        acc[6] = sn * bl(s.w); acc[7] = sn * bh(s.w);
    } else {
        #pragma unroll
        for (int v = 0; v < 8; v++) acc[v] = 0.f;
    }

    int e0 = rowptr[node];
    int e1 = rowptr[node + 1];
    for (int e = e0; e < e1; e += 16) {
        int i0 = e + oct;
        int i1 = e + 8 + oct;
        int2 m0 = (i0 < e1) ? meta[i0] : make_int2(0, 0);
        int2 m1 = (i1 < e1) ? meta[i1] : make_int2(0, 0);
        float n0 = __int_as_float(m0.y);
        float n1 = __int_as_float(m1.y);
        uint4 r0 = Hv[(size_t)m0.x * 8 + sub];
        uint4 r1 = Hv[(size_t)m1.x * 8 + sub];
        acc[0] = fmaf(n0, bl(r0.x), acc[0]); acc[1] = fmaf(n0, bh(r0.x), acc[1]);
        acc[2] = fmaf(n0, bl(r0.y), acc[2]); acc[3] = fmaf(n0, bh(r0.y), acc[3]);
        acc[4] = fmaf(n0, bl(r0.z), acc[4]); acc[5] = fmaf(n0, bh(r0.z), acc[5]);
        acc[6] = fmaf(n0, bl(r0.w), acc[6]); acc[7] = fmaf(n0, bh(r0.w), acc[7]);
        acc[0] = fmaf(n1, bl(r1.x), acc[0]); acc[1] = fmaf(n1, bh(r1.x), acc[1]);
        acc[2] = fmaf(n1, bl(r1.y), acc[2]); acc[3] = fmaf(n1, bh(r1.y), acc[3]);
        acc[4] = fmaf(n1, bl(r1.z), acc[4]); acc[5] = fmaf(n1, bh(r1.z), acc[5]);
        acc[6] = fmaf(n1, bl(r1.w), acc[6]); acc[7] = fmaf(n1, bh(r1.w), acc[7]);
    }

    #pragma unroll
    for (int v = 0; v < 8; v++) {
        acc[v] += __shfl_xor(acc[v], 8);
        acc[v] += __shfl_xor(acc[v], 16);
        acc[v] += __shfl_xor(acc[v], 32);
    }

    if (oct == 0) {
        uint4 o;
        o.x = packbf(acc[0], acc[1]);
        o.y = packbf(acc[2], acc[3]);
        o.z = packbf(acc[4], acc[5]);
        o.w = packbf(acc[6], acc[7]);
        ((uint4*)Hout)[(size_t)node * 8 + sub] = o;
    }
}

// ---------------------------------------------------------------- dense GEMM (A bf16)
// out[n][j] = (relu)( sum_k A[n][k] * W[k][j] + bias[j] ),  j in [0,128)
template <int K>
__global__ __launch_bounds__(256) void gemm_kernel(const unsigned short* __restrict__ A,
                                                   const float* __restrict__ Wm,
                                                   const float* __restrict__ bias,
                                                   unsigned short* __restrict__ out,
                                                   int N, int applyRelu) {
    constexpr int KC = 64;
    __shared__ float Wl[KC][128];
    __shared__ float Al[32][KC + 4];

    int t = threadIdx.x;
    int tileBase = blockIdx.x * 32;
    int cj = (t & 31) * 4;
    int nb = (t >> 5) * 4;

    float4 acc[4];
    #pragma unroll
    for (int nn = 0; nn < 4; nn++) acc[nn] = make_float4(0.f, 0.f, 0.f, 0.f);

    for (int kc = 0; kc < K; kc += KC) {
        const float4* Wg = (const float4*)(Wm + (size_t)kc * 128);
        #pragma unroll
        for (int i = 0; i < (KC * 128 / 4) / 256; i++) {
            int idx = i * 256 + t;
            ((float4*)Wl)[idx] = Wg[idx];
        }
        // stage A tile (32 x KC bf16 -> f32)
        #pragma unroll
        for (int i = 0; i < (32 * KC / 4) / 256; i++) {
            int fi = i * 256 + t;
            int r  = fi >> 4;          // KC/4 = 16 groups per row
            int c4 = fi & 15;
            int node = tileBase + r;
            uint2 v = make_uint2(0u, 0u);
            if (node < N) v = ((const uint2*)(A + (size_t)node * K + kc))[c4];
            Al[r][c4 * 4 + 0] = bl(v.x);
            Al[r][c4 * 4 + 1] = bh(v.x);
            Al[r][c4 * 4 + 2] = bl(v.y);
            Al[r][c4 * 4 + 3] = bh(v.y);
        }
        __syncthreads();

        #pragma unroll
        for (int k = 0; k < KC; k += 4) {
            const float4 w0 = *(const float4*)&Wl[k + 0][cj];
            const float4 w1 = *(const float4*)&Wl[k + 1][cj];
            const float4 w2 = *(const float4*)&Wl[k + 2][cj];
            const float4 w3 = *(const float4*)&Wl[k + 3][cj];
            #pragma unroll
            for (int nn = 0; nn < 4; nn++) {
                const float4 h = *(const float4*)&Al[nb + nn][k];
                acc[nn].x = fmaf(h.x, w0.x, fmaf(h.y, w1.x, fmaf(h.z, w2.x, fmaf(h.w, w3.x, acc[nn].x))));
                acc[nn].y = fmaf(h.x, w0.y, fmaf(h.y, w1.y, fmaf(h.z, w2.y, fmaf(h.w, w3.y, acc[nn].y))));
                acc[nn].z = fmaf(h.x, w0.z, fmaf(h.y, w1.z, fmaf(h.z, w2.z, fmaf(h.w, w3.z, acc[nn].z))));
                acc[nn].w = fmaf(h.x, w0.w, fmaf(h.y, w1.w, fmaf(h.z, w2.w, fmaf(h.w, w3.w, acc[nn].w))));
            }
        }
        __syncthreads();
    }

    float4 bv = make_float4(0.f, 0.f, 0.f, 0.f);
    if (bias) bv = *(const float4*)(bias + cj);
    #pragma unroll
    for (int nn = 0; nn < 4; nn++) {
        int node = tileBase + nb + nn;
        if (node < N) {
            float4 r;
            r.x = acc[nn].x + bv.x;
            r.y = acc[nn].y + bv.y;
            r.z = acc[nn].z + bv.z;
            r.w = acc[nn].w + bv.w;
            if (applyRelu) {
                r.x = fmaxf(r.x, 0.f); r.y = fmaxf(r.y, 0.f);
                r.z = fmaxf(r.z, 0.f); r.w = fmaxf(r.w, 0.f);
            }
            ((uint2*)out)[(size_t)node * 32 + (cj >> 2)] = make_uint2(packbf(r.x, r.y), packbf(r.z, r.w));
        }
    }
}

// ---------------------------------------------------------------- pool + MLP
__device__ __forceinline__ int lowerb(const int* a, int n, int v) {
    int lo = 0, hi = n;
    while (lo < hi) {
        int m = (lo + hi) >> 1;
        if (a[m] < v) lo = m + 1; else hi = m;
    }
    return lo;
}

// one block (256 threads) per graph: 4-way row-split pooling (uint = 2 bf16 cols/lane),
// then 128->128->128->10 MLP in fp32.
__global__ __launch_bounds__(256) void pool_mlp_kernel(const unsigned short* __restrict__ H,
                                                       const int* __restrict__ batch,
                                                       const float* __restrict__ mW0, const float* __restrict__ mb0,
                                                       const float* __restrict__ mW1, const float* __restrict__ mb1,
                                                       const float* __restrict__ mW2, const float* __restrict__ mb2,
                                                       float* __restrict__ out, int N) {
    int b = blockIdx.x;
    int t = threadIdx.x;
    int jw = t & 63;      // uint index in row (2 bf16)
    int g  = t >> 6;      // row parity 0..3
    int lo = lowerb(batch, N, b);
    int hi = lowerb(batch, N, b + 1);

    const uint32* Hu = (const uint32*)H;   // row = 64 uints
    float f0 = 0.f, f1 = 0.f;
    for (int n = lo + g; n < hi; n += 4) {
        uint32 v = Hu[(size_t)n * 64 + jw];
        f0 += bl(v);
        f1 += bh(v);
    }

    __shared__ float part[4][HID];
    __shared__ float l0[HID];
    __shared__ float l1[HID];
    part[g][jw * 2 + 0] = f0;
    part[g][jw * 2 + 1] = f1;
    __syncthreads();
    if (t < 128) l0[t] = part[0][t] + part[1][t] + part[2][t] + part[3][t];
    __syncthreads();

    if (t < 128) {
        int j = t;
        float a0 = mb0[j], a1 = 0.f, a2 = 0.f, a3 = 0.f;
        #pragma unroll 4
        for (int k = 0; k < HID; k += 4) {
            a0 = fmaf(l0[k + 0], mW0[(k + 0) * HID + j], a0);
            a1 = fmaf(l0[k + 1], mW0[(k + 1) * HID + j], a1);
            a2 = fmaf(l0[k + 2], mW0[(k + 2) * HID + j], a2);
            a3 = fmaf(l0[k + 3], mW0[(k + 3) * HID + j], a3);
        }
        l1[j] = fmaxf((a0 + a1) + (a2 + a3), 0.f);
    }
    __syncthreads();

    float c = 0.f;
    if (t < 128) {
        int j = t;
        float a0 = mb1[j], a1 = 0.f, a2 = 0.f, a3 = 0.f;
        #pragma unroll 4
        for (int k = 0; k < HID; k += 4) {
            a0 = fmaf(l1[k + 0], mW1[(k + 0) * HID + j], a0);
            a1 = fmaf(l1[k + 1], mW1[(k + 1) * HID + j], a1);
            a2 = fmaf(l1[k + 2], mW1[(k + 2) * HID + j], a2);
            a3 = fmaf(l1[k + 3], mW1[(k + 3) * HID + j], a3);
        }
        c = fmaxf((a0 + a1) + (a2 + a3), 0.f);
    }
    __syncthreads();
    if (t < 128) l0[t] = c;
    __syncthreads();

    if (t < N_CLASSES) {
        float a0 = mb2[t], a1 = 0.f, a2 = 0.f, a3 = 0.f;
        #pragma unroll 4
        for (int k = 0; k < HID; k += 4) {
            a0 = fmaf(l0[k + 0], mW2[(k + 0) * N_CLASSES + t], a0);
            a1 = fmaf(l0[k + 1], mW2[(k + 1) * N_CLASSES + t], a1);
            a2 = fmaf(l0[k + 2], mW2[(k + 2) * N_CLASSES + t], a2);
            a3 = fmaf(l0[k + 3], mW2[(k + 3) * N_CLASSES + t], a3);
        }
        out[b * N_CLASSES + t] = (a0 + a1) + (a2 + a3);
    }
}

// ---------------------------------------------------------------- launch
extern "C" void kernel_launch(void* const* d_in, const int* in_sizes, int n_in,
                              void* d_out, int out_size, void* d_ws, size_t ws_size,
                              hipStream_t stream) {
    const float* x     = (const float*)d_in[0];
    const int*   ei    = (const int*)d_in[1];
    const int*   batch = (const int*)d_in[2];
    const float* W0  = (const float*)d_in[3];
    const float* b0  = (const float*)d_in[4];
    const float* W1  = (const float*)d_in[5];
    const float* b1  = (const float*)d_in[6];
    const float* W2  = (const float*)d_in[7];
    const float* b2  = (const float*)d_in[8];
    const float* mW0 = (const float*)d_in[9];
    const float* mb0 = (const float*)d_in[10];
    const float* mW1 = (const float*)d_in[11];
    const float* mb1 = (const float*)d_in[12];
    const float* mW2 = (const float*)d_in[13];
    const float* mb2 = (const float*)d_in[14];
    float* out = (float*)d_out;

    const int N = N_NODES, E = N_EDGES;
    const int* src = ei;
    const int* dst = ei + E;

    char* w = (char*)d_ws;
    auto alloc = [&](size_t bytes) -> void* {
        void* p = (void*)w;
        w += (bytes + 255) & ~(size_t)255;
        return p;
    };
    int*   cnt    = (int*)alloc((size_t)N * 4);
    int*   rowptr = (int*)alloc((size_t)(N + 1) * 4);
    int*   cursor = (int*)alloc((size_t)N * 4);
    int2*  meta   = (int2*)alloc((size_t)E * 8);
    float* dinv   = (float*)alloc((size_t)N * 4);
    int*   bsum   = (int*)alloc(256 * 4);
    unsigned short* xb   = (unsigned short*)alloc((size_t)N * F_IN * 2);
    unsigned short* bufA = (unsigned short*)alloc((size_t)N * HID * 2);
    unsigned short* bufB = (unsigned short*)alloc((size_t)N * HID * 2);

    const int NB  = (N + 255) / 256;   // 196
    const int EB  = (E + 255) / 256;   // 3125
    const int SPB = (N + 3) / 4;       // 12500
    const int GB  = (N + 31) / 32;     // 1563
    const int XB  = (N * F_IN / 4 + 255) / 256;  // x conversion blocks

    // ---- CSR build + x conversion
    zero_int_kernel<<<NB, 256, 0, stream>>>(cnt, N);
    hist_kernel<<<EB, 256, 0, stream>>>(dst, cnt, E);
    f2b_kernel<<<XB, 256, 0, stream>>>((const float4*)x, (uint2*)xb, N * F_IN / 4);
    scan1_kernel<<<NB, 256, 0, stream>>>(cnt, rowptr, bsum, N);
    scan2_kernel<<<1, 256, 0, stream>>>(bsum, NB);
    scan3_kernel<<<NB, 256, 0, stream>>>(cnt, rowptr, bsum, cursor, dinv, N);
    scatter_kernel<<<EB, 256, 0, stream>>>(src, dst, dinv, cursor, meta, E);

    // ---- layer 0: aggregate raw x (A@x), then GEMM with bias+relu
    spmm64_kernel<<<SPB, 256, 0, stream>>>(rowptr, meta, dinv, xb, bufA, N);
    gemm_kernel<64><<<GB, 256, 0, stream>>>(bufA, W0, b0, bufB, N, 1);

    // ---- layer 1: t = h0@W1, h1 = relu(A@t + b1)
    gemm_kernel<128><<<GB, 256, 0, stream>>>(bufB, W1, nullptr, bufA, N, 0);
    spmm128_kernel<<<SPB, 256, 0, stream>>>(rowptr, meta, dinv, bufA, b1, bufB, N, 1);

    // ---- layer 2: t = h1@W2, h2 = relu(A@t + b2)
    gemm_kernel<128><<<GB, 256, 0, stream>>>(bufB, W2, nullptr, bufA, N, 0);
    spmm128_kernel<<<SPB, 256, 0, stream>>>(rowptr, meta, dinv, bufA, b2, bufB, N, 1);

    // ---- pool + MLP
    pool_mlp_kernel<<<NUM_GRAPHS, 256, 0, stream>>>(bufB, batch, mW0, mb0, mW1, mb1, mW2, mb2, out, N);
}

// Round 4
// 232.892 us; speedup vs baseline: 1.7601x; 1.3760x over previous
//
#include <hip/hip_runtime.h>
#include <hip/hip_bf16.h>
#include <stdint.h>

#define N_NODES   50000
#define N_EDGES   800000
#define F_IN      64
#define HID       128
#define N_CLASSES 10
#define NUM_GRAPHS 512

typedef unsigned int uint32;
typedef __attribute__((ext_vector_type(8))) short bf16x8;
typedef __attribute__((ext_vector_type(4))) float f32x4;

// ---------------- bf16 helpers (storage bf16, math fp32) ----------------
__device__ __forceinline__ float bl(uint32 w) { return __uint_as_float(w << 16); }
__device__ __forceinline__ float bh(uint32 w) { return __uint_as_float(w & 0xffff0000u); }
__device__ __forceinline__ uint32 packbf(float a, float b) {   // RNE, (a=low, b=high)
    uint32 ua = __float_as_uint(a), ub = __float_as_uint(b);
    ua = (ua + 0x7fffu + ((ua >> 16) & 1u)) >> 16;
    ub = (ub + 0x7fffu + ((ub >> 16) & 1u)) >> 16;
    return ua | (ub << 16);
}
__device__ __forceinline__ unsigned short packbf1(float a) {
    uint32 ua = __float_as_uint(a);
    return (unsigned short)((ua + 0x7fffu + ((ua >> 16) & 1u)) >> 16);
}

// ---------------------------------------------------------------- utilities
__global__ __launch_bounds__(256) void zero_int_kernel(int* p, int n) {
    int i = blockIdx.x * 256 + threadIdx.x;
    if (i < n) p[i] = 0;
}

// count in-degree AND record per-edge rank (arrival order within dst row)
__global__ __launch_bounds__(256) void hist_kernel(const int* __restrict__ dst,
                                                   int* __restrict__ cnt,
                                                   int* __restrict__ rank, int E) {
    int e = blockIdx.x * 256 + threadIdx.x;
    if (e < E) rank[e] = atomicAdd(&cnt[dst[e]], 1);
}

// f32 -> bf16 conversion (4 elems/thread)
__global__ __launch_bounds__(256) void f2b_kernel(const float4* __restrict__ in,
                                                  uint2* __restrict__ out, int n) {
    int i = blockIdx.x * 256 + threadIdx.x;
    if (i < n) {
        float4 v = in[i];
        out[i] = make_uint2(packbf(v.x, v.y), packbf(v.z, v.w));
    }
}

// W [K][128] f32  ->  Wt [128][K+8] bf16 (transposed, padded) ; all 3 weights in one launch
__global__ __launch_bounds__(256) void w2bt_kernel(const float* __restrict__ W0, unsigned short* __restrict__ W0t,
                                                   const float* __restrict__ W1, unsigned short* __restrict__ W1t,
                                                   const float* __restrict__ W2, unsigned short* __restrict__ W2t) {
    int i = blockIdx.x * 256 + threadIdx.x;
    // W0: 64*128 elems ; W1,W2: 128*128
    if (i < 64 * 128) {
        int k = i >> 7, j = i & 127;
        W0t[j * (64 + 8) + k] = packbf1(W0[i]);
    }
    i -= 64 * 128;
    if (i >= 0 && i < 128 * 128) {
        int k = i >> 7, j = i & 127;
        W1t[j * (128 + 8) + k] = packbf1(W1[i]);
        W2t[j * (128 + 8) + k] = packbf1(W2[i]);
    }
}

// ------------------------------------------------------------ prefix scan
__global__ __launch_bounds__(256) void scan1_kernel(const int* __restrict__ cnt,
                                                    int* __restrict__ rowptr,
                                                    int* __restrict__ bsum, int N) {
    __shared__ int s[256];
    int t = threadIdx.x;
    int i = blockIdx.x * 256 + t;
    int v = (i < N) ? cnt[i] : 0;
    s[t] = v;
    __syncthreads();
    #pragma unroll
    for (int d = 1; d < 256; d <<= 1) {
        int a = (t >= d) ? s[t - d] : 0;
        __syncthreads();
        s[t] += a;
        __syncthreads();
    }
    if (i < N) rowptr[i + 1] = s[t];
    if (t == 255) bsum[blockIdx.x] = s[255];
}

__global__ __launch_bounds__(256) void scan2_kernel(int* __restrict__ bsum, int NB) {
    __shared__ int s[256];
    int t = threadIdx.x;
    int v = (t < NB) ? bsum[t] : 0;
    s[t] = v;
    __syncthreads();
    #pragma unroll
    for (int d = 1; d < 256; d <<= 1) {
        int a = (t >= d) ? s[t - d] : 0;
        __syncthreads();
        s[t] += a;
        __syncthreads();
    }
    if (t < NB) bsum[t] = s[t] - v;
}

__global__ __launch_bounds__(256) void scan3_kernel(const int* __restrict__ cnt,
                                                    int* __restrict__ rowptr,
                                                    const int* __restrict__ bsum,
                                                    int* __restrict__ rowstart,
                                                    float* __restrict__ dinv, int N) {
    int i = blockIdx.x * 256 + threadIdx.x;
    if (i < N) {
        int c = cnt[i];
        int inc = rowptr[i + 1] + bsum[blockIdx.x];
        rowptr[i + 1] = inc;
        rowstart[i] = inc - c;
        dinv[i] = rsqrtf((float)(c + 1));
    }
    if (i == 0) rowptr[0] = 0;
}

// place edges into CSR slots (no atomics: slot = rowstart[dst] + rank[e])
__global__ __launch_bounds__(256) void scatter_kernel(const int* __restrict__ src,
                                                      const int* __restrict__ dst,
                                                      const int* __restrict__ rank,
                                                      const int* __restrict__ rowstart,
                                                      const float* __restrict__ dinv,
                                                      int2* __restrict__ meta, int E) {
    int e = blockIdx.x * 256 + threadIdx.x;
    if (e < E) {
        int s = src[e], d = dst[e];
        int slot = rowstart[d] + rank[e];
        meta[slot] = make_int2(s, __float_as_int(dinv[s] * dinv[d]));
    }
}

// ---------------------------------------------------------------- SpMM 128-wide bf16
__global__ __launch_bounds__(256) void spmm128_kernel(const int* __restrict__ rowptr,
                                                      const int2* __restrict__ meta,
                                                      const float* __restrict__ dinv,
                                                      const unsigned short* __restrict__ Hin,
                                                      const float* __restrict__ bias,
                                                      unsigned short* __restrict__ Hout,
                                                      int N, int applyRelu) {
    int wave = threadIdx.x >> 6;
    int lane = threadIdx.x & 63;
    int node = blockIdx.x * 4 + wave;
    if (node >= N) return;
    int q   = lane >> 4;
    int sub = lane & 15;

    const uint4* Hv = (const uint4*)Hin;     // row = 16 chunks of 8 bf16
    float di = dinv[node];
    float sn = di * di;

    float acc[8];
    if (q == 0) {
        uint4 s = Hv[(size_t)node * 16 + sub];
        acc[0] = sn * bl(s.x); acc[1] = sn * bh(s.x);
        acc[2] = sn * bl(s.y); acc[3] = sn * bh(s.y);
        acc[4] = sn * bl(s.z); acc[5] = sn * bh(s.z);
        acc[6] = sn * bl(s.w); acc[7] = sn * bh(s.w);
    } else {
        #pragma unroll
        for (int v = 0; v < 8; v++) acc[v] = 0.f;
    }

    int e0 = rowptr[node];
    int e1 = rowptr[node + 1];
    for (int e = e0; e < e1; e += 8) {
        int i0 = e + q;
        int i1 = e + 4 + q;
        int2 m0 = (i0 < e1) ? meta[i0] : make_int2(0, 0);
        int2 m1 = (i1 < e1) ? meta[i1] : make_int2(0, 0);
        float n0 = __int_as_float(m0.y);
        float n1 = __int_as_float(m1.y);
        uint4 r0 = Hv[(size_t)m0.x * 16 + sub];
        uint4 r1 = Hv[(size_t)m1.x * 16 + sub];
        acc[0] = fmaf(n0, bl(r0.x), acc[0]); acc[1] = fmaf(n0, bh(r0.x), acc[1]);
        acc[2] = fmaf(n0, bl(r0.y), acc[2]); acc[3] = fmaf(n0, bh(r0.y), acc[3]);
        acc[4] = fmaf(n0, bl(r0.z), acc[4]); acc[5] = fmaf(n0, bh(r0.z), acc[5]);
        acc[6] = fmaf(n0, bl(r0.w), acc[6]); acc[7] = fmaf(n0, bh(r0.w), acc[7]);
        acc[0] = fmaf(n1, bl(r1.x), acc[0]); acc[1] = fmaf(n1, bh(r1.x), acc[1]);
        acc[2] = fmaf(n1, bl(r1.y), acc[2]); acc[3] = fmaf(n1, bh(r1.y), acc[3]);
        acc[4] = fmaf(n1, bl(r1.z), acc[4]); acc[5] = fmaf(n1, bh(r1.z), acc[5]);
        acc[6] = fmaf(n1, bl(r1.w), acc[6]); acc[7] = fmaf(n1, bh(r1.w), acc[7]);
    }

    #pragma unroll
    for (int v = 0; v < 8; v++) {
        acc[v] += __shfl_xor(acc[v], 16);
        acc[v] += __shfl_xor(acc[v], 32);
    }

    if (q == 0) {
        if (bias) {
            const float4* bp = (const float4*)(bias + sub * 8);
            float4 b0 = bp[0], b1 = bp[1];
            acc[0] += b0.x; acc[1] += b0.y; acc[2] += b0.z; acc[3] += b0.w;
            acc[4] += b1.x; acc[5] += b1.y; acc[6] += b1.z; acc[7] += b1.w;
        }
        if (applyRelu) {
            #pragma unroll
            for (int v = 0; v < 8; v++) acc[v] = fmaxf(acc[v], 0.f);
        }
        uint4 o;
        o.x = packbf(acc[0], acc[1]);
        o.y = packbf(acc[2], acc[3]);
        o.z = packbf(acc[4], acc[5]);
        o.w = packbf(acc[6], acc[7]);
        ((uint4*)Hout)[(size_t)node * 16 + sub] = o;
    }
}

// ---------------------------------------------------------------- SpMM 64-wide bf16
__global__ __launch_bounds__(256) void spmm64_kernel(const int* __restrict__ rowptr,
                                                     const int2* __restrict__ meta,
                                                     const float* __restrict__ dinv,
                                                     const unsigned short* __restrict__ Hin,
                                                     unsigned short* __restrict__ Hout, int N) {
    int wave = threadIdx.x >> 6;
    int lane = threadIdx.x & 63;
    int node = blockIdx.x * 4 + wave;
    if (node >= N) return;
    int oct = lane >> 3;
    int sub = lane & 7;

    const uint4* Hv = (const uint4*)Hin;     // row = 8 chunks of 8 bf16
    float di = dinv[node];
    float sn = di * di;

    float acc[8];
    if (oct == 0) {
        uint4 s = Hv[(size_t)node * 8 + sub];
        acc[0] = sn * bl(s.x); acc[1] = sn * bh(s.x);
        acc[2] = sn * bl(s.y); acc[3] = sn * bh(s.y);
        acc[4] = sn * bl(s.z); acc[5] = sn * bh(s.z);
        acc[6] = sn * bl(s.w); acc[7] = sn * bh(s.w);
    } else {
        #pragma unroll
        for (int v = 0; v < 8; v++) acc[v] = 0.f;
    }

    int e0 = rowptr[node];
    int e1 = rowptr[node + 1];
    for (int e = e0; e < e1; e += 16) {
        int i0 = e + oct;
        int i1 = e + 8 + oct;
        int2 m0 = (i0 < e1) ? meta[i0] : make_int2(0, 0);
        int2 m1 = (i1 < e1) ? meta[i1] : make_int2(0, 0);
        float n0 = __int_as_float(m0.y);
        float n1 = __int_as_float(m1.y);
        uint4 r0 = Hv[(size_t)m0.x * 8 + sub];
        uint4 r1 = Hv[(size_t)m1.x * 8 + sub];
        acc[0] = fmaf(n0, bl(r0.x), acc[0]); acc[1] = fmaf(n0, bh(r0.x), acc[1]);
        acc[2] = fmaf(n0, bl(r0.y), acc[2]); acc[3] = fmaf(n0, bh(r0.y), acc[3]);
        acc[4] = fmaf(n0, bl(r0.z), acc[4]); acc[5] = fmaf(n0, bh(r0.z), acc[5]);
        acc[6] = fmaf(n0, bl(r0.w), acc[6]); acc[7] = fmaf(n0, bh(r0.w), acc[7]);
        acc[0] = fmaf(n1, bl(r1.x), acc[0]); acc[1] = fmaf(n1, bh(r1.x), acc[1]);
        acc[2] = fmaf(n1, bl(r1.y), acc[2]); acc[3] = fmaf(n1, bh(r1.y), acc[3]);
        acc[4] = fmaf(n1, bl(r1.z), acc[4]); acc[5] = fmaf(n1, bh(r1.z), acc[5]);
        acc[6] = fmaf(n1, bl(r1.w), acc[6]); acc[7] = fmaf(n1, bh(r1.w), acc[7]);
    }

    #pragma unroll
    for (int v = 0; v < 8; v++) {
        acc[v] += __shfl_xor(acc[v], 8);
        acc[v] += __shfl_xor(acc[v], 16);
        acc[v] += __shfl_xor(acc[v], 32);
    }

    if (oct == 0) {
        uint4 o;
        o.x = packbf(acc[0], acc[1]);
        o.y = packbf(acc[2], acc[3]);
        o.z = packbf(acc[4], acc[5]);
        o.w = packbf(acc[6], acc[7]);
        ((uint4*)Hout)[(size_t)node * 8 + sub] = o;
    }
}

// ---------------------------------------------------------------- MFMA GEMM (bf16)
// out[n][j] = (relu)( sum_k A[n][k]*W[k][j] + bias[j] ), j in [0,128).
// Block: 4 waves x 16 rows = 64 rows, 128 cols. Wt staged in LDS ([128][K+8] bf16).
// A-frag (16x32): lane l -> row l&15, k = (l>>4)*8..+7  (16B global load/lane)
// B-frag (32x16): lane l -> col l&15, k = (l>>4)*8..+7  (ds_read_b128 from Wt[col][k])
// C (16x16): col = lane&15, row = (lane>>4)*4 + reg   [verified m89]
template <int K>
__global__ __launch_bounds__(256) void gemm_mfma_kernel(const unsigned short* __restrict__ A,
                                                        const unsigned short* __restrict__ Wt,
                                                        const float* __restrict__ bias,
                                                        unsigned short* __restrict__ out,
                                                        int N, int applyRelu) {
    constexpr int KP = K + 8;
    __shared__ unsigned short Wl[128 * KP];

    int t = threadIdx.x;
    constexpr int TOT = 128 * KP * 2 / 16;     // uint4 chunks
    #pragma unroll
    for (int i = 0; i < (TOT + 255) / 256; i++) {
        int idx = i * 256 + t;
        if (idx < TOT) ((uint4*)Wl)[idx] = ((const uint4*)Wt)[idx];
    }
    __syncthreads();

    int wave = t >> 6;
    int lane = t & 63;
    int rowBase = blockIdx.x * 64 + wave * 16;
    int arow = rowBase + (lane & 15);
    if (arow >= N) arow = N - 1;               // clamp (stores predicated)
    int kchunk = lane >> 4;                    // 0..3
    int colSub = lane & 15;

    f32x4 acc[8];
    #pragma unroll
    for (int i = 0; i < 8; i++) acc[i] = (f32x4)0.0f;

    #pragma unroll
    for (int s = 0; s < K / 32; s++) {
        bf16x8 a = *(const bf16x8*)(A + (size_t)arow * K + s * 32 + kchunk * 8);
        #pragma unroll
        for (int tl = 0; tl < 8; tl++) {
            bf16x8 b = *(const bf16x8*)(Wl + (tl * 16 + colSub) * KP + s * 32 + kchunk * 8);
            acc[tl] = __builtin_amdgcn_mfma_f32_16x16x32_bf16(a, b, acc[tl], 0, 0, 0);
        }
    }

    int rowOff = (lane >> 4) * 4;
    #pragma unroll
    for (int tl = 0; tl < 8; tl++) {
        int col = tl * 16 + colSub;
        float bv = bias ? bias[col] : 0.f;
        #pragma unroll
        for (int r = 0; r < 4; r++) {
            int row = rowBase + rowOff + r;
            if (row < N) {
                float v = acc[tl][r] + bv;
                if (applyRelu) v = fmaxf(v, 0.f);
                out[(size_t)row * 128 + col] = packbf1(v);
            }
        }
    }
}

// ---------------------------------------------------------------- pool + MLP
__device__ __forceinline__ int lowerb(const int* a, int n, int v) {
    int lo = 0, hi = n;
    while (lo < hi) {
        int m = (lo + hi) >> 1;
        if (a[m] < v) lo = m + 1; else hi = m;
    }
    return lo;
}

__global__ __launch_bounds__(256) void pool_mlp_kernel(const unsigned short* __restrict__ H,
                                                       const int* __restrict__ batch,
                                                       const float* __restrict__ mW0, const float* __restrict__ mb0,
                                                       const float* __restrict__ mW1, const float* __restrict__ mb1,
                                                       const float* __restrict__ mW2, const float* __restrict__ mb2,
                                                       float* __restrict__ out, int N) {
    int b = blockIdx.x;
    int t = threadIdx.x;
    int jw = t & 63;      // uint index in row (2 bf16)
    int g  = t >> 6;      // row parity 0..3
    int lo = lowerb(batch, N, b);
    int hi = lowerb(batch, N, b + 1);

    const uint32* Hu = (const uint32*)H;   // row = 64 uints
    float f0 = 0.f, f1 = 0.f;
    for (int n = lo + g; n < hi; n += 4) {
        uint32 v = Hu[(size_t)n * 64 + jw];
        f0 += bl(v);
        f1 += bh(v);
    }

    __shared__ float part[4][HID];
    __shared__ float l0[HID];
    __shared__ float l1[HID];
    part[g][jw * 2 + 0] = f0;
    part[g][jw * 2 + 1] = f1;
    __syncthreads();
    if (t < 128) l0[t] = part[0][t] + part[1][t] + part[2][t] + part[3][t];
    __syncthreads();

    if (t < 128) {
        int j = t;
        float a0 = mb0[j], a1 = 0.f, a2 = 0.f, a3 = 0.f;
        #pragma unroll 4
        for (int k = 0; k < HID; k += 4) {
            a0 = fmaf(l0[k + 0], mW0[(k + 0) * HID + j], a0);
            a1 = fmaf(l0[k + 1], mW0[(k + 1) * HID + j], a1);
            a2 = fmaf(l0[k + 2], mW0[(k + 2) * HID + j], a2);
            a3 = fmaf(l0[k + 3], mW0[(k + 3) * HID + j], a3);
        }
        l1[j] = fmaxf((a0 + a1) + (a2 + a3), 0.f);
    }
    __syncthreads();

    float c = 0.f;
    if (t < 128) {
        int j = t;
        float a0 = mb1[j], a1 = 0.f, a2 = 0.f, a3 = 0.f;
        #pragma unroll 4
        for (int k = 0; k < HID; k += 4) {
            a0 = fmaf(l1[k + 0], mW1[(k + 0) * HID + j], a0);
            a1 = fmaf(l1[k + 1], mW1[(k + 1) * HID + j], a1);
            a2 = fmaf(l1[k + 2], mW1[(k + 2) * HID + j], a2);
            a3 = fmaf(l1[k + 3], mW1[(k + 3) * HID + j], a3);
        }
        c = fmaxf((a0 + a1) + (a2 + a3), 0.f);
    }
    __syncthreads();
    if (t < 128) l0[t] = c;
    __syncthreads();

    if (t < N_CLASSES) {
        float a0 = mb2[t], a1 = 0.f, a2 = 0.f, a3 = 0.f;
        #pragma unroll 4
        for (int k = 0; k < HID; k += 4) {
            a0 = fmaf(l0[k + 0], mW2[(k + 0) * N_CLASSES + t], a0);
            a1 = fmaf(l0[k + 1], mW2[(k + 1) * N_CLASSES + t], a1);
            a2 = fmaf(l0[k + 2], mW2[(k + 2) * N_CLASSES + t], a2);
            a3 = fmaf(l0[k + 3], mW2[(k + 3) * N_CLASSES + t], a3);
        }
        out[b * N_CLASSES + t] = (a0 + a1) + (a2 + a3);
    }
}

// ---------------------------------------------------------------- launch
extern "C" void kernel_launch(void* const* d_in, const int* in_sizes, int n_in,
                              void* d_out, int out_size, void* d_ws, size_t ws_size,
                              hipStream_t stream) {
    const float* x     = (const float*)d_in[0];
    const int*   ei    = (const int*)d_in[1];
    const int*   batch = (const int*)d_in[2];
    const float* W0  = (const float*)d_in[3];
    const float* b0  = (const float*)d_in[4];
    const float* W1  = (const float*)d_in[5];
    const float* b1  = (const float*)d_in[6];
    const float* W2  = (const float*)d_in[7];
    const float* b2  = (const float*)d_in[8];
    const float* mW0 = (const float*)d_in[9];
    const float* mb0 = (const float*)d_in[10];
    const float* mW1 = (const float*)d_in[11];
    const float* mb1 = (const float*)d_in[12];
    const float* mW2 = (const float*)d_in[13];
    const float* mb2 = (const float*)d_in[14];
    float* out = (float*)d_out;

    const int N = N_NODES, E = N_EDGES;
    const int* src = ei;
    const int* dst = ei + E;

    char* w = (char*)d_ws;
    auto alloc = [&](size_t bytes) -> void* {
        void* p = (void*)w;
        w += (bytes + 255) & ~(size_t)255;
        return p;
    };
    int*   cnt      = (int*)alloc((size_t)N * 4);
    int*   rowptr   = (int*)alloc((size_t)(N + 1) * 4);
    int*   rowstart = (int*)alloc((size_t)N * 4);
    int*   rank     = (int*)alloc((size_t)E * 4);
    int2*  meta     = (int2*)alloc((size_t)E * 8);
    float* dinv     = (float*)alloc((size_t)N * 4);
    int*   bsum     = (int*)alloc(256 * 4);
    unsigned short* xb   = (unsigned short*)alloc((size_t)N * F_IN * 2);
    unsigned short* bufA = (unsigned short*)alloc((size_t)N * HID * 2);
    unsigned short* bufB = (unsigned short*)alloc((size_t)N * HID * 2);
    unsigned short* W0t  = (unsigned short*)alloc((size_t)128 * (64 + 8) * 2);
    unsigned short* W1t  = (unsigned short*)alloc((size_t)128 * (128 + 8) * 2);
    unsigned short* W2t  = (unsigned short*)alloc((size_t)128 * (128 + 8) * 2);

    const int NB  = (N + 255) / 256;   // 196
    const int EB  = (E + 255) / 256;   // 3125
    const int SPB = (N + 3) / 4;       // 12500
    const int GB  = (N + 63) / 64;     // 782
    const int XB  = (N * F_IN / 4 + 255) / 256;
    const int WB  = (64 * 128 + 128 * 128 + 255) / 256;  // 96

    // ---- CSR build + conversions
    zero_int_kernel<<<NB, 256, 0, stream>>>(cnt, N);
    hist_kernel<<<EB, 256, 0, stream>>>(dst, cnt, rank, E);
    f2b_kernel<<<XB, 256, 0, stream>>>((const float4*)x, (uint2*)xb, N * F_IN / 4);
    w2bt_kernel<<<WB, 256, 0, stream>>>(W0, W0t, W1, W1t, W2, W2t);
    scan1_kernel<<<NB, 256, 0, stream>>>(cnt, rowptr, bsum, N);
    scan2_kernel<<<1, 256, 0, stream>>>(bsum, NB);
    scan3_kernel<<<NB, 256, 0, stream>>>(cnt, rowptr, bsum, rowstart, dinv, N);
    scatter_kernel<<<EB, 256, 0, stream>>>(src, dst, rank, rowstart, dinv, meta, E);

    // ---- layer 0: aggregate raw x (A@x), then GEMM with bias+relu
    spmm64_kernel<<<SPB, 256, 0, stream>>>(rowptr, meta, dinv, xb, bufA, N);
    gemm_mfma_kernel<64><<<GB, 256, 0, stream>>>(bufA, W0t, b0, bufB, N, 1);

    // ---- layer 1: t = h0@W1, h1 = relu(A@t + b1)
    gemm_mfma_kernel<128><<<GB, 256, 0, stream>>>(bufB, W1t, nullptr, bufA, N, 0);
    spmm128_kernel<<<SPB, 256, 0, stream>>>(rowptr, meta, dinv, bufA, b1, bufB, N, 1);

    // ---- layer 2: t = h1@W2, h2 = relu(A@t + b2)
    gemm_mfma_kernel<128><<<GB, 256, 0, stream>>>(bufB, W2t, nullptr, bufA, N, 0);
    spmm128_kernel<<<SPB, 256, 0, stream>>>(rowptr, meta, dinv, bufA, b2, bufB, N, 1);

    // ---- pool + MLP
    pool_mlp_kernel<<<NUM_GRAPHS, 256, 0, stream>>>(bufB, batch, mW0, mb0, mW1, mb1, mW2, mb2, out, N);
}